// Round 8
// baseline (2374.042 us; speedup 1.0000x reference)
//
#include <hip/hip_runtime.h>

typedef unsigned short u16;
typedef _Float16 f16x8_t __attribute__((ext_vector_type(8)));
typedef _Float16 f16x4_t __attribute__((ext_vector_type(4)));
typedef short    i16x8_t __attribute__((ext_vector_type(8)));
typedef short    i16x4_t __attribute__((ext_vector_type(4)));
typedef float    f32x4_t __attribute__((ext_vector_type(4)));

// ---- helpers ---------------------------------------------------------------
static __device__ __forceinline__ u16 f2h(float f) {
  _Float16 h = (_Float16)f;  // RNE
  return __builtin_bit_cast(u16, h);
}
static __device__ __forceinline__ f32x4_t mfma16h(i16x8_t a, i16x8_t b, f32x4_t c) {
  return __builtin_amdgcn_mfma_f32_16x16x32_f16(
      __builtin_bit_cast(f16x8_t, a), __builtin_bit_cast(f16x8_t, b), c, 0, 0, 0);
}
static __device__ __forceinline__ float sigmoidf_(float x) { return 1.f / (1.f + __expf(-x)); }
static __device__ __forceinline__ float tanhf_(float x) { return 1.f - 2.f / (__expf(2.f * x) + 1.f); }

// ---- prep: Wi / Wh packs in MFMA fragment order ----------------------------
// wipack[dir][nt64][kb4][lane64][e8]: n = nt*16+mrow, k = kb*32+quad*8+e -> Wi[k][n]
// whpack[dir][w16][g4][kb8][lane64][e8]: n = g*256+w*16+mrow, kh = kb*32+quad*8+e -> Wh[kh][n]
__global__ __launch_bounds__(256) void prep_wpack2(const float* __restrict__ Wi_f,
                                                   const float* __restrict__ Wh_f,
                                                   const float* __restrict__ Wi_r,
                                                   const float* __restrict__ Wh_r,
                                                   u16* __restrict__ wipack,
                                                   u16* __restrict__ whpack) {
  int id = blockIdx.x * 256 + threadIdx.x;
  if (id < 262144) {  // wipack: 2*64*4*512
    int e = id & 7, lane = (id >> 3) & 63, kb = (id >> 9) & 3, nt = (id >> 11) & 63, dir = id >> 17;
    int mrow = lane & 15, quad = lane >> 4;
    int n = nt * 16 + mrow, k = kb * 32 + quad * 8 + e;
    const float* Wi = dir ? Wi_r : Wi_f;
    wipack[id] = f2h(Wi[k * 1024 + n]);
    return;
  }
  id -= 262144;
  if (id < 524288) {  // whpack: 2*16*4*8*512
    int e = id & 7, lane = (id >> 3) & 63, kb = (id >> 9) & 7, g = (id >> 12) & 3, w = (id >> 14) & 15, dir = id >> 18;
    int mrow = lane & 15, quad = lane >> 4;
    int n = g * 256 + w * 16 + mrow, k = kb * 32 + quad * 8 + e;
    const float* Wh = dir ? Wh_r : Wh_f;
    whpack[id] = f2h(Wh[k * 1024 + n]);
  }
}

// ---- prep: MLP W^T in f16 (W1[512][256], W2[256][256], W3[256][128]) -------
__global__ __launch_bounds__(256) void prep_small(const float* __restrict__ W1,
                                                  const float* __restrict__ W2,
                                                  const float* __restrict__ W3,
                                                  u16* __restrict__ w1t,
                                                  u16* __restrict__ w2t,
                                                  u16* __restrict__ w3t) {
  int id = blockIdx.x * 256 + threadIdx.x;
  if (id < 131072) { int n = id >> 9, k = id & 511; w1t[id] = f2h(W1[k * 256 + n]); return; }
  id -= 131072;
  if (id < 65536) { int n = id >> 8, k = id & 255; w2t[id] = f2h(W2[k * 256 + n]); return; }
  id -= 65536;
  if (id < 32768) { int n = id >> 8, k = id & 255; w3t[id] = f2h(W3[k * 128 + n]); }
}

// ---- bidirectional LSTM v5: Gx-hoisted, chunked ----------------------------
// 64 blocks = dir(2) x bg(32), M=16 batch rows, 1024 threads = 16 waves.
// Wave w owns j-cols [w*16,(w+1)*16) x all 4 gates (in-register update).
// Per 16-step chunk: GEMM phase computes Gx = x@Wi + bias into gxs (global,
// per-block, C-layout-swizzled), then 16 recurrent steps with K=256 (h only).
// Wh kb0-1 LDS-resident (128 KB); kb2-7 streamed (384 KB/step).
__global__ __launch_bounds__(1024, 4) void lstm_kernel(
    const float* __restrict__ x0, const u16* __restrict__ wipack,
    const u16* __restrict__ whpack,
    const float* __restrict__ bi_f, const float* __restrict__ bh_f,
    const float* __restrict__ bi_r, const float* __restrict__ bh_r,
    u16* __restrict__ gxs, u16* __restrict__ x1) {
  __shared__ __align__(16) u16 lw[16][4][2][64][8];  // 128 KB resident Wh kb0,1
  __shared__ __align__(16) u16 ah[2][16][272];       // h panels; ah[0] overlays xs[2][16][136]

  const int tid = threadIdx.x, lane = tid & 63, w = tid >> 6;
  const int dir = blockIdx.x >> 5, b0 = (blockIdx.x & 31) * 16;
  const int mrow = lane & 15, quad = lane >> 4;
  const float* bi = dir ? bi_r : bi_f;
  const float* bh = dir ? bh_r : bh_f;
  const u16* wip = wipack + dir * 131072;
  const u16* whp = whpack + dir * 262144;
  u16* gxb = gxs + (size_t)blockIdx.x * 262144;  // [tl16][w16][g4][lane64][r4]

  float bias_[4];
#pragma unroll
  for (int g = 0; g < 4; ++g) {
    int n = g * 256 + w * 16 + mrow;
    bias_[g] = bi[n] + bh[n];
  }
  float c_[4] = {0.f, 0.f, 0.f, 0.f};

  // load LDS-resident Wh slice (kb 0,1): 8192 fragments of 16 B
#pragma unroll
  for (int i = 0; i < 8; ++i) {
    int f = i * 1024 + tid;
    int l = f & 63, kb = (f >> 6) & 1, g = (f >> 7) & 3, ww = f >> 9;
    *(i16x8_t*)&lw[ww][g][kb][l][0] =
        *(const i16x8_t*)(whp + (((ww * 4 + g) * 8 + kb) * 64 + l) * 8);
  }
  // h_{-1} = 0 in ah[1]
  { u16* a1 = &ah[1][0][0]; for (int i = tid; i < 16 * 272; i += 1024) a1[i] = 0; }

  u16* xs = &ah[0][0][0];  // [2][16][136] staging during GEMM phase

#pragma unroll 1
  for (int ch = 0; ch < 8; ++ch) {
    // ---- chunk GEMM: Gx for t in [16ch, 16ch+16), 8 sub-chunks of 2 t ----
#pragma unroll 1
    for (int sub = 0; sub < 8; ++sub) {
      __syncthreads();  // prior readers of xs/ah[0] done
      {
        int row = tid >> 5, tlq = row >> 4, bl = row & 15, c4 = (tid & 31) * 4;
        int tt = ch * 16 + sub * 2 + tlq;
        int teff = dir ? (127 - tt) : tt;
        float4 v = *(const float4*)(x0 + (((size_t)(b0 + bl) * 128 + teff) << 7) + c4);
        u16* dst = xs + (size_t)(tlq * 16 + bl) * 136 + c4;
        dst[0] = f2h(v.x); dst[1] = f2h(v.y); dst[2] = f2h(v.z); dst[3] = f2h(v.w);
      }
      __syncthreads();  // xs staged
#pragma unroll
      for (int g = 0; g < 4; ++g) {
        const int nt = g * 16 + w;
        i16x8_t wi[4];
#pragma unroll
        for (int kb = 0; kb < 4; ++kb)
          wi[kb] = *(const i16x8_t*)(wip + ((nt * 4 + kb) * 64 + lane) * 8);
#pragma unroll
        for (int tlq = 0; tlq < 2; ++tlq) {
          i16x8_t af[4];
#pragma unroll
          for (int kb = 0; kb < 4; ++kb)
            af[kb] = *(const i16x8_t*)(xs + (size_t)(tlq * 16 + mrow) * 136 + kb * 32 + quad * 8);
          f32x4_t a = {bias_[g], bias_[g], bias_[g], bias_[g]};
#pragma unroll
          for (int kb = 0; kb < 4; ++kb) a = mfma16h(af[kb], wi[kb], a);
          int tl = sub * 2 + tlq;
          i16x4_t o;
          o[0] = (short)f2h(a[0]); o[1] = (short)f2h(a[1]);
          o[2] = (short)f2h(a[2]); o[3] = (short)f2h(a[3]);
          *(i16x4_t*)(gxb + (((size_t)(tl * 16 + w) * 4 + g) * 64 + lane) * 4) = o;
        }
      }
    }

    // ---- 16 recurrent steps ----
#pragma unroll 1
    for (int st = 0; st < 16; ++st) {
      const int t = ch * 16 + st;
      const int par = t & 1;
      __syncthreads();  // gxs stores drained (vmcnt0); ah hazards ordered

      // coalesced flush h_{t-1} -> x1
      if (t > 0) {
        int fm = tid >> 6, fj = (tid & 63) * 4;
        i16x4_t hh = *(const i16x4_t*)&ah[par ^ 1][fm][fj];
        *(i16x4_t*)(x1 + ((size_t)((b0 + fm) * 128 + (t - 1))) * 512 + dir * 256 + fj) = hh;
      }

      // Gx acc-init loads (8 B per gate)
      i16x4_t gxv[4];
#pragma unroll
      for (int g = 0; g < 4; ++g)
        gxv[g] = *(const i16x4_t*)(gxb + (((size_t)(st * 16 + w) * 4 + g) * 64 + lane) * 4);

      // A-fragments from h panel (K=256)
      i16x8_t af[8];
#pragma unroll
      for (int kb = 0; kb < 8; ++kb)
        af[kb] = *(const i16x8_t*)&ah[par ^ 1][mrow][kb * 32 + quad * 8];

      f32x4_t acc[4];
#pragma unroll
      for (int g = 0; g < 4; ++g) {
        const u16* wpg = whp + (((w * 4 + g) * 8) * 64 + lane) * 8;
        i16x8_t wf[6];
#pragma unroll
        for (int kb = 2; kb < 8; ++kb)
          wf[kb - 2] = *(const i16x8_t*)(wpg + kb * 512);
        i16x8_t l0 = *(const i16x8_t*)&lw[w][g][0][lane][0];
        i16x8_t l1 = *(const i16x8_t*)&lw[w][g][1][lane][0];
        f16x4_t gh = __builtin_bit_cast(f16x4_t, gxv[g]);
        f32x4_t a = {(float)gh[0], (float)gh[1], (float)gh[2], (float)gh[3]};
        a = mfma16h(af[0], l0, a);
        a = mfma16h(af[1], l1, a);
#pragma unroll
        for (int kb = 2; kb < 8; ++kb) a = mfma16h(af[kb], wf[kb - 2], a);
        acc[g] = a;
      }

      // in-register gate update; lane owns (m = quad*4+r, j = w*16+mrow)
      {
        const int jcol = (w << 4) | mrow;
#pragma unroll
        for (int r = 0; r < 4; ++r) {
          float cv = sigmoidf_(acc[0][r]) * c_[r] + sigmoidf_(acc[1][r]) * tanhf_(acc[2][r]);
          c_[r] = cv;
          float hv = sigmoidf_(acc[3][r]) * tanhf_(cv);
          ah[par][(quad << 2) | r][jcol] = f2h(hv);
        }
      }
    }
  }
  // epilogue: flush h_127 (t=127 odd -> ah[1])
  __syncthreads();
  {
    int fm = tid >> 6, fj = (tid & 63) * 4;
    i16x4_t hh = *(const i16x4_t*)&ah[1][fm][fj];
    *(i16x4_t*)(x1 + ((size_t)((b0 + fm) * 128 + 127)) * 512 + dir * 256 + fj) = hh;
  }
}

// ---- fused MLP + heads (unchanged — passing) -------------------------------
__global__ __launch_bounds__(512, 1) void mlp_kernel(
    const u16* __restrict__ x1, const u16* __restrict__ w1t,
    const u16* __restrict__ w2t, const u16* __restrict__ w3t,
    const float* __restrict__ b1, const float* __restrict__ b2,
    const float* __restrict__ b3, float* __restrict__ out) {
  __shared__ __align__(16) u16 X2[128][264];
  __shared__ __align__(16) u16 X3[128][264];
  const int tid = threadIdx.x;
  const int lane = tid & 63, wv = tid >> 6;
  const int mrow = lane & 15, quad = lane >> 4;
  const int r0 = blockIdx.x * 128;
  const f32x4_t zero4 = {0.f, 0.f, 0.f, 0.f};

  // stage 1: X2[128][256] = leaky(x1[128,512] @ W1 + b1)
  {
    f32x4_t acc[16];
#pragma unroll
    for (int n = 0; n < 16; ++n) acc[n] = zero4;
    for (int kb = 0; kb < 16; ++kb) {
      int k = kb * 32 + quad * 8;
      i16x8_t a = *(const i16x8_t*)(x1 + (size_t)(r0 + wv * 16 + mrow) * 512 + k);
#pragma unroll
      for (int n = 0; n < 16; ++n) {
        i16x8_t b = *(const i16x8_t*)(w1t + (n * 16 + mrow) * 512 + k);
        acc[n] = mfma16h(a, b, acc[n]);
      }
    }
#pragma unroll
    for (int n = 0; n < 16; ++n)
#pragma unroll
      for (int r = 0; r < 4; ++r) {
        int m = wv * 16 + quad * 4 + r;
        int col = n * 16 + mrow;
        float v = acc[n][r] + b1[col];
        v = v > 0.f ? v : 0.1f * v;
        X2[m][col] = f2h(v);
      }
  }
  __syncthreads();

  // stage 2: X3[128][256] = leaky(X2 @ W2 + b2), K=256
  {
    f32x4_t acc[16];
#pragma unroll
    for (int n = 0; n < 16; ++n) acc[n] = zero4;
#pragma unroll
    for (int kb = 0; kb < 8; ++kb) {
      int k = kb * 32 + quad * 8;
      i16x8_t a = *(const i16x8_t*)&X2[wv * 16 + mrow][k];
#pragma unroll
      for (int n = 0; n < 16; ++n) {
        i16x8_t b = *(const i16x8_t*)(w2t + (n * 16 + mrow) * 256 + k);
        acc[n] = mfma16h(a, b, acc[n]);
      }
    }
#pragma unroll
    for (int n = 0; n < 16; ++n)
#pragma unroll
      for (int r = 0; r < 4; ++r) {
        int m = wv * 16 + quad * 4 + r;
        int col = n * 16 + mrow;
        float v = acc[n][r] + b2[col];
        v = v > 0.f ? v : 0.1f * v;
        X3[m][col] = f2h(v);
      }
  }
  __syncthreads();

  // stage 3: XF[128][128] = X3 @ W3 + b3 (fp32; overlays dead X2)
  float (*XF)[130] = (float (*)[130]) & X2[0][0];
  {
    f32x4_t acc[8];
#pragma unroll
    for (int n = 0; n < 8; ++n) acc[n] = zero4;
#pragma unroll
    for (int kb = 0; kb < 8; ++kb) {
      int k = kb * 32 + quad * 8;
      i16x8_t a = *(const i16x8_t*)&X3[wv * 16 + mrow][k];
#pragma unroll
      for (int n = 0; n < 8; ++n) {
        i16x8_t b = *(const i16x8_t*)(w3t + (n * 16 + mrow) * 256 + k);
        acc[n] = mfma16h(a, b, acc[n]);
      }
    }
#pragma unroll
    for (int n = 0; n < 8; ++n)
#pragma unroll
      for (int r = 0; r < 4; ++r) {
        int m = wv * 16 + quad * 4 + r;
        int col = n * 16 + mrow;
        XF[m][col] = acc[n][r] + b3[col];
      }
  }
  __syncthreads();

  // heads: cols 0:64 sigmoid; softmax over [64,72), [72,88), [88,128)
  if (tid < 128) {
    int row = tid;
    float* xr = XF[row];
    float* op = out + (size_t)(r0 + row) * 128;
    for (int cc = 0; cc < 64; ++cc) op[cc] = sigmoidf_(xr[cc]);
  } else if (tid < 256) {
    int row = tid - 128;
    float* xr = XF[row];
    float* op = out + (size_t)(r0 + row) * 128;
    const int s0s[3] = {64, 72, 88};
    const int s1s[3] = {72, 88, 128};
    for (int s = 0; s < 3; ++s) {
      int s0 = s0s[s], s1 = s1s[s];
      float mx = xr[s0];
      for (int qq = s0 + 1; qq < s1; ++qq) mx = fmaxf(mx, xr[qq]);
      float sum = 0.f;
      for (int qq = s0; qq < s1; ++qq) { float e = __expf(xr[qq] - mx); xr[qq] = e; sum += e; }
      float inv = 1.f / sum;
      for (int qq = s0; qq < s1; ++qq) op[qq] = xr[qq] * inv;
    }
  }
}

// ---- launch ----------------------------------------------------------------
extern "C" void kernel_launch(void* const* d_in, const int* in_sizes, int n_in,
                              void* d_out, int out_size, void* d_ws, size_t ws_size,
                              hipStream_t stream) {
  const float* x0   = (const float*)d_in[0];
  const float* Wi_f = (const float*)d_in[1];
  const float* bi_f = (const float*)d_in[2];
  const float* Wh_f = (const float*)d_in[3];
  const float* bh_f = (const float*)d_in[4];
  const float* Wi_r = (const float*)d_in[5];
  const float* bi_r = (const float*)d_in[6];
  const float* Wh_r = (const float*)d_in[7];
  const float* bh_r = (const float*)d_in[8];
  const float* W1 = (const float*)d_in[9];
  const float* b1 = (const float*)d_in[10];
  const float* W2 = (const float*)d_in[11];
  const float* b2 = (const float*)d_in[12];
  const float* W3 = (const float*)d_in[13];
  const float* b3 = (const float*)d_in[14];
  float* out = (float*)d_out;

  char* ws = (char*)d_ws;
  u16* w1t    = (u16*)(ws + 0);          // 262144 B
  u16* w2t    = (u16*)(ws + 262144);     // 131072 B
  u16* w3t    = (u16*)(ws + 393216);     // 65536 B
  u16* wipack = (u16*)(ws + 458752);     // 524288 B
  u16* whpack = (u16*)(ws + 983040);     // 1048576 B
  u16* gxs    = (u16*)(ws + 2031616);    // 33554432 B
  u16* x1     = (u16*)(ws + 35586048);   // 67108864 B

  hipLaunchKernelGGL(prep_wpack2, dim3(3072), dim3(256), 0, stream,
                     Wi_f, Wh_f, Wi_r, Wh_r, wipack, whpack);
  hipLaunchKernelGGL(prep_small, dim3(896), dim3(256), 0, stream,
                     W1, W2, W3, w1t, w2t, w3t);
  hipLaunchKernelGGL(lstm_kernel, dim3(64), dim3(1024), 0, stream,
                     x0, wipack, whpack, bi_f, bh_f, bi_r, bh_r, gxs, x1);
  hipLaunchKernelGGL(mlp_kernel, dim3(512), dim3(512), 0, stream,
                     x1, w1t, w2t, w3t, b1, b2, b3, out);
}